// Round 4
// baseline (73.301 us; speedup 1.0000x reference)
//
#include <hip/hip_runtime.h>

// Problem dims (compile-time constants from the reference)
#define BB 512
#define HH 32
#define LL 7
#define SS 5
#define OO 8
#define NN (BB * HH)          // 16384 independent cells
#define DIST_THRESHOLD 0.1f

// One thread per (n, l, obj-quarter): 32 lanes per cell.
// 524288 threads = 2048 blocks x 256.
// Lane layout within a 32-group: bits[4:2] = l (7 == idle), bits[1:0] = oq.
// NOTE: no min-waves launch_bounds arg — R3's (256,8) build core-dumped at
// runtime; kernel needs ~32 VGPR so occupancy is naturally high anyway.
__global__ __launch_bounds__(256)
void PrimitiveCollisionCost_19533511262442_kernel(
    const float* __restrict__ pos,    // [N,L,3]
    const float* __restrict__ rot,    // [N,L,3,3]
    const float* __restrict__ off,    // [L,S,3]
    const float* __restrict__ srad,   // [L,S]
    const float* __restrict__ oc,     // [O,3]
    const float* __restrict__ orad,   // [O]
    const float* __restrict__ weight, // [1]
    float* __restrict__ out)          // [N]
{
    const int t  = blockIdx.x * blockDim.x + threadIdx.x;
    const int n  = t >> 5;        // cell index
    const int l  = (t >> 2) & 7;  // link index (7 == idle lane)
    const int oq = t & 3;         // obj quarter -> objs {2*oq, 2*oq+1}

    float best = -1e30f;

    if (l < LL) {
        const float* posn = pos + (size_t)n * (LL * 3) + l * 3;
        const float* rotn = rot + (size_t)n * (LL * 9) + l * 9;

        const float px = posn[0];
        const float py = posn[1];
        const float pz = posn[2];

        const float r00 = rotn[0];
        const float r01 = rotn[1];
        const float r02 = rotn[2];
        const float r10 = rotn[3];
        const float r11 = rotn[4];
        const float r12 = rotn[5];
        const float r20 = rotn[6];
        const float r21 = rotn[7];
        const float r22 = rotn[8];

        // This thread's two world objects
        const int o0 = oq * 2;
        const float c0x = oc[o0 * 3 + 0], c0y = oc[o0 * 3 + 1], c0z = oc[o0 * 3 + 2];
        const float c1x = oc[o0 * 3 + 3], c1y = oc[o0 * 3 + 4], c1z = oc[o0 * 3 + 5];
        const float ro0 = orad[o0], ro1 = orad[o0 + 1];

#pragma unroll
        for (int s = 0; s < SS; ++s) {
            const float ox = off[(l * SS + s) * 3 + 0];
            const float oy = off[(l * SS + s) * 3 + 1];
            const float oz = off[(l * SS + s) * 3 + 2];
            const float rs = srad[l * SS + s];

            // world-frame sphere center: c = R @ o + p
            const float cx = r00 * ox + r01 * oy + r02 * oz + px;
            const float cy = r10 * ox + r11 * oy + r12 * oz + py;
            const float cz = r20 * ox + r21 * oy + r22 * oz + pz;

            {
                const float dx = cx - c0x, dy = cy - c0y, dz = cz - c0z;
                const float d  = sqrtf(dx * dx + dy * dy + dz * dz);
                best = fmaxf(best, rs + ro0 - d);
            }
            {
                const float dx = cx - c1x, dy = cy - c1y, dz = cz - c1z;
                const float d  = sqrtf(dx * dx + dy * dy + dz * dz);
                best = fmaxf(best, rs + ro1 - d);
            }
        }
    }

    // max over the 4 obj-quarter lanes (xor within low 2 bits)
    best = fmaxf(best, __shfl_xor(best, 1, 64));
    best = fmaxf(best, __shfl_xor(best, 2, 64));

    // clip(best + 0.1, 0, 0.2) / 0.25  — idle lanes (best = -1e30) clamp to 0
    float dist = fminf(fmaxf(best + DIST_THRESHOLD, 0.0f), 0.2f) * 4.0f;

    // sum over the 8 link slots (bits [4:2])
    dist += __shfl_xor(dist, 4, 64);
    dist += __shfl_xor(dist, 8, 64);
    dist += __shfl_xor(dist, 16, 64);

    if ((t & 31) == 0) {
        out[n] = weight[0] * dist;
    }
}

extern "C" void kernel_launch(void* const* d_in, const int* in_sizes, int n_in,
                              void* d_out, int out_size, void* d_ws, size_t ws_size,
                              hipStream_t stream) {
    const float* pos    = (const float*)d_in[0];  // link_pos_seq  [B,H,L,3]
    const float* rot    = (const float*)d_in[1];  // link_rot_seq  [B,H,L,3,3]
    const float* off    = (const float*)d_in[2];  // sphere_offsets [L,S,3]
    const float* srad   = (const float*)d_in[3];  // sphere_radii  [L,S]
    const float* oc     = (const float*)d_in[4];  // obj_centers   [O,3]
    const float* orad   = (const float*)d_in[5];  // obj_radii     [O]
    const float* weight = (const float*)d_in[6];  // scalar
    float* out = (float*)d_out;                   // [B,H] = [N]

    constexpr int block = 256;
    constexpr int grid  = (NN * 32) / block;  // 2048 blocks

    PrimitiveCollisionCost_19533511262442_kernel<<<grid, block, 0, stream>>>(
        pos, rot, off, srad, oc, orad, weight, out);
}